// Round 7
// baseline (1495.766 us; speedup 1.0000x reference)
//
#include <hip/hip_runtime.h>
#include <hip/hip_bf16.h>

// Grouped SwiGLU experts: E=8, T=2048, D_IN=2048, D_H=5632. FP32 in/out.
// r11: fix r10's structural 4-way bank conflict. LDS halves use an 8x8-chunk
// block-transposed layout: chunk L(row,col16) = (row>>3)*64 + col16*8 + (row&7).
// 32x32 fragment reads (fixed col, 32 rows) become 8-lane runs of CONSECUTIVE
// 16B chunks -> 0 conflicts; gld_lds writes stay lane-linear; stage source is
// the inverse map (each 128B row segment fully covered per instruction).
// Rest identical to r10: 32x32x16 MFMA, ring-10, 2 barriers/step, vmcnt(6),
// persistent grid=256, compiler-scheduled step interior.

#define NEXP 8
#define TT   2048
#define DIN  2048
#define DH   5632
#define KP   2080   // padded K pitch (elems) for X / WgT / WdT

using short8 = __attribute__((ext_vector_type(8))) short;   // 8 x bf16
using f32x16 = __attribute__((ext_vector_type(16))) float;  // 32x32 MFMA acc

static __device__ __forceinline__ unsigned short f2bf(float f) {
    unsigned int i = __float_as_uint(f);
    return (unsigned short)((i + 0x7FFFu + ((i >> 16) & 1u)) >> 16);  // RNE
}
static __device__ __forceinline__ void gld16(const void* g, void* l) {
    __builtin_amdgcn_global_load_lds(
        (const __attribute__((address_space(1))) void*)g,
        (__attribute__((address_space(3))) void*)l, 16, 0, 0);
}

// ---------------------------------------------------------------------------
// Fused G/U GEMM (persistent, ring-10, 32x32x16, block-transposed LDS).
// 11 tiles of 256x128, BK=64. 8 waves 2Mx4N; per wave 4 M-tiles x {G,U}.
// ---------------------------------------------------------------------------
__global__ __launch_bounds__(512, 2) void gemm_gu(
    const unsigned short* __restrict__ Xb,   // [E][T][KP] bf16
    const unsigned short* __restrict__ Wgt,  // [E][DH][KP] bf16 (K-major)
    const unsigned short* __restrict__ Wdt,  // [E][DH][KP] bf16
    unsigned short* __restrict__ Hb)         // [E][T][DH] bf16
{
    __shared__ __align__(16) unsigned short lds[81920];  // 160 KB = 10 x 16 KB

    const int tid  = threadIdx.x;
    const int wave = tid >> 6, lane = tid & 63;
    const int l31 = lane & 31, lh = lane >> 5;
    const int wr = wave >> 2, wc = wave & 3;     // 2M x 4N wave grid

    const int bid = blockIdx.x;                  // 256 blocks = 8 XCD * 32 CU
    const int e   = bid & 7;                     // expert == XCD
    const int cu  = bid >> 3;                    // [0,32)
    const int m0  = (cu & 7) * 256;              // constant per CU
    const int nb  = cu >> 3;                     // [0,4): n0(i) = (4i+nb)*128

    const unsigned short* Ae = Xb + (size_t)e * TT * KP + (size_t)m0 * KP;
    unsigned short* He = Hb + (size_t)e * TT * DH;

    // Stage-side: lane handles LDS chunks c0=tid, c1=tid+512 (lane-linear
    // dest). Inverse of L(row,col): row = (c>>6)*8 + (c&7), col16 = (c>>3)&7.
    const int c0 = tid, c1 = 512 + tid;
    const int srow0 = ((c0 >> 6) << 3) + (c0 & 7), scol0 = ((c0 >> 3) & 7) * 8;
    const int srow1 = ((c1 >> 6) << 3) + (c1 & 7), scol1 = ((c1 >> 3) & 7) * 8;
    const size_t loff0 = (size_t)srow0 * KP + scol0;
    const size_t loff1 = (size_t)srow1 * KP + scol1;
    const int wvoff = wave * 1024;

    // Read-side byte offsets: byte = (r>>3)*1024 + (ks*2+lh)*128 + (r&7)*16.
    int ibA[2][4], ibB[4];
#pragma unroll
    for (int rg = 0; rg < 2; ++rg)
#pragma unroll
        for (int ks = 0; ks < 4; ++ks) {
            const int r = wr * 64 + rg * 32 + l31;
            ibA[rg][ks] = (r >> 3) * 1024 + (ks * 2 + lh) * 128 + (r & 7) * 16;
        }
#pragma unroll
    for (int ks = 0; ks < 4; ++ks) {
        const int r = wc * 32 + l31;
        ibB[ks] = (r >> 3) * 1024 + (ks * 2 + lh) * 128 + (r & 7) * 16;
    }

    f32x16 accG[4] = {}, accU[4] = {};           // 4 M-tiles each

    char* ldsb = (char*)lds;
    const char* ldsc = (const char*)lds;
    auto stageA = [&](int ro, int kk, int so) {
        gld16(Ae + (size_t)ro * KP + kk + loff0, ldsb + so + wvoff);
        gld16(Ae + (size_t)ro * KP + kk + loff1, ldsb + so + 8192 + wvoff);
    };
    auto stageW = [&](const unsigned short* p, int kk, int so) {
        gld16(p + kk + loff0, ldsb + so + wvoff);
        gld16(p + kk + loff1, ldsb + so + 8192 + wvoff);
    };
    auto w10 = [](int x) { return x >= 10 ? x - 10 : x; };

    const size_t NSTEP = (size_t)512 * KP;       // 4*128 weight rows per tile
    const unsigned short* Gc = Wgt + (size_t)e * DH * KP + (size_t)(nb * 128) * KP;
    const unsigned short* Dc = Wdt + (size_t)e * DH * KP + (size_t)(nb * 128) * KP;

    // Prologue: g0 {A0,G,D,A1} -> slots 0..3; g1 {A0,G,D} -> 4..6.
    stageA(0, 0, 0 << 14);  stageW(Gc, 0, 1 << 14);  stageW(Dc, 0, 2 << 14);  stageA(128, 0, 3 << 14);
    stageA(0, 64, 4 << 14); stageW(Gc, 64, 5 << 14); stageW(Dc, 64, 6 << 14);
    asm volatile("s_waitcnt vmcnt(6)" ::: "memory");
    asm volatile("s_barrier" ::: "memory");

    int q = 0;                                   // (4g) % 10
    for (int i = 0; i < 11; ++i) {
        const unsigned short* Gn = Gc + NSTEP;
        const unsigned short* Dn = Dc + NSTEP;
        for (int t = 0; t < 32; ++t) {
            const int g = (i << 5) + t;          // global step, [0,352)
            const int sA0 = q << 14;
            const int sG  = w10(q + 1) << 14;
            const int sD  = w10(q + 2) << 14;
            const int sA1 = w10(q + 3) << 14;
            const int stA1 = w10(q + 7) << 14;   // stale (read at g-1)
            const int stA0 = w10(q + 8) << 14;   // stale
            const int stG  = w10(q + 9) << 14;   // stale
            const int stD  = sA0;                // turnaround (read this step)

            // Early stages into stale slots.
            if (i < 10 || t + 1 < 32)
                stageA(128, ((t + 1) & 31) * 64, stA1);
            if (i < 10 || t + 2 < 32) {
                stageA(0, ((t + 2) & 31) * 64, stA0);
                stageW((t + 2 < 32) ? Gc : Gn, ((t + 2) & 31) * 64, stG);
            }

            // Reads + MFMA, compiler-scheduled (counted lgkmcnt auto-emitted).
            short8 aF[4][4], gF[4], dF[4];
#pragma unroll
            for (int ks = 0; ks < 4; ++ks) {
                aF[0][ks] = *(const short8*)(ldsc + sA0 + ibA[0][ks]);
                aF[1][ks] = *(const short8*)(ldsc + sA0 + ibA[1][ks]);
                aF[2][ks] = *(const short8*)(ldsc + sA1 + ibA[0][ks]);
                aF[3][ks] = *(const short8*)(ldsc + sA1 + ibA[1][ks]);
                gF[ks] = *(const short8*)(ldsc + sG + ibB[ks]);
                dF[ks] = *(const short8*)(ldsc + sD + ibB[ks]);
#pragma unroll
                for (int mt = 0; mt < 4; ++mt) {
                    accG[mt] = __builtin_amdgcn_mfma_f32_32x32x16_bf16(
                        aF[mt][ks], gF[ks], accG[mt], 0, 0, 0);
                    accU[mt] = __builtin_amdgcn_mfma_f32_32x32x16_bf16(
                        aF[mt][ks], dF[ks], accU[mt], 0, 0, 0);
                }
            }

            // Drain this wave's ds_reads before the turnaround-slot stage.
            asm volatile("s_waitcnt lgkmcnt(0)" ::: "memory");
            __builtin_amdgcn_sched_barrier(0);
            asm volatile("s_barrier" ::: "memory");
            if (i < 10 || t + 2 < 32)
                stageW((t + 2 < 32) ? Dc : Dn, ((t + 2) & 31) * 64, stD);
            if (g < 350)       asm volatile("s_waitcnt vmcnt(6)" ::: "memory");
            else if (g == 350) asm volatile("s_waitcnt vmcnt(0)" ::: "memory");
            asm volatile("s_barrier" ::: "memory");
            q = w10(q + 4);
        }

        // Tile epilogue: H = silu(G)*U.
        // 32x32 C/D: col = lane&31, row = (reg&3) + 8*(reg>>2) + 4*(lane>>5).
        const int n0i = (4 * i + nb) * 128;
        const int col = n0i + wc * 32 + l31;
#pragma unroll
        for (int mt = 0; mt < 4; ++mt) {
            const int row_b = m0 + (mt >> 1) * 128 + wr * 64 + (mt & 1) * 32 + 4 * lh;
#pragma unroll
            for (int j = 0; j < 16; ++j) {
                const int row = row_b + (j & 3) + 8 * (j >> 2);
                const float gv = accG[mt][j];
                const float uv = accU[mt][j];
                const float h = gv / (1.f + __expf(-gv)) * uv;
                He[(size_t)row * DH + col] = f2bf(h);
            }
        }
#pragma unroll
        for (int mt = 0; mt < 4; ++mt)
#pragma unroll
            for (int j = 0; j < 16; ++j) { accG[mt][j] = 0.f; accU[mt][j] = 0.f; }
        Gc = Gn; Dc = Dn;
    }
}

// ---------------------------------------------------------------------------
// Out-GEMM (persistent, ring-10, 32x32x16, block-transposed LDS).
// 2 tiles of 256x256, BK=64. Per wave 4 M-tiles x 2 N-tiles.
// ---------------------------------------------------------------------------
__global__ __launch_bounds__(512, 2) void gemm_out(
    const unsigned short* __restrict__ Ab,   // H [E][T][DH] bf16
    const unsigned short* __restrict__ Btb,  // WuT [E][DIN][DH] bf16
    float* __restrict__ Cf)                  // [E][T][DIN] fp32
{
    __shared__ __align__(16) unsigned short lds[81920];  // 160 KB

    const int tid  = threadIdx.x;
    const int wave = tid >> 6, lane = tid & 63;
    const int l31 = lane & 31, lh = lane >> 5;
    const int wr = wave >> 2, wc = wave & 3;     // 2M x 4N

    const int bid = blockIdx.x;                  // 256
    const int e   = bid & 7;
    const int cu  = bid >> 3;                    // [0,32)
    const int m0  = (cu & 7) * 256;
    const int nb  = cu >> 3;                     // n0(i) = (4i+nb)*256

    const unsigned short* Ae = Ab + (size_t)e * TT * DH + (size_t)m0 * DH;

    const int c0 = tid, c1 = 512 + tid;
    const int srow0 = ((c0 >> 6) << 3) + (c0 & 7), scol0 = ((c0 >> 3) & 7) * 8;
    const int srow1 = ((c1 >> 6) << 3) + (c1 & 7), scol1 = ((c1 >> 3) & 7) * 8;
    const size_t loff0 = (size_t)srow0 * DH + scol0;
    const size_t loff1 = (size_t)srow1 * DH + scol1;
    const int wvoff = wave * 1024;

    int ibA[2][4], ibB[4];
#pragma unroll
    for (int rg = 0; rg < 2; ++rg)
#pragma unroll
        for (int ks = 0; ks < 4; ++ks) {
            const int r = wr * 64 + rg * 32 + l31;
            ibA[rg][ks] = (r >> 3) * 1024 + (ks * 2 + lh) * 128 + (r & 7) * 16;
        }
#pragma unroll
    for (int ks = 0; ks < 4; ++ks) {
        const int r = wc * 32 + l31;
        ibB[ks] = (r >> 3) * 1024 + (ks * 2 + lh) * 128 + (r & 7) * 16;
    }

    f32x16 acc[4][2] = {};                       // M-tile x N-tile

    char* ldsb = (char*)lds;
    const char* ldsc = (const char*)lds;
    auto stageA = [&](int ro, int kk, int so) {
        gld16(Ae + (size_t)ro * DH + kk + loff0, ldsb + so + wvoff);
        gld16(Ae + (size_t)ro * DH + kk + loff1, ldsb + so + 8192 + wvoff);
    };
    auto stageB = [&](const unsigned short* base, int co, int kk, int so) {
        gld16(base + (size_t)co * DH + kk + loff0, ldsb + so + wvoff);
        gld16(base + (size_t)co * DH + kk + loff1, ldsb + so + 8192 + wvoff);
    };
    auto w10 = [](int x) { return x >= 10 ? x - 10 : x; };

    const size_t NSTEP = (size_t)1024 * DH;      // 4*256 B rows per tile
    const unsigned short* Bc = Btb + (size_t)e * DIN * DH + (size_t)(nb * 256) * DH;

    stageA(0, 0, 0 << 14); stageB(Bc, 0, 0, 1 << 14); stageB(Bc, 128, 0, 2 << 14); stageA(128, 0, 3 << 14);
    stageA(0, 64, 4 << 14); stageB(Bc, 0, 64, 5 << 14); stageB(Bc, 128, 64, 6 << 14);
    asm volatile("s_waitcnt vmcnt(6)" ::: "memory");
    asm volatile("s_barrier" ::: "memory");

    int q = 0;
    for (int i = 0; i < 2; ++i) {
        const unsigned short* Bn = Bc + NSTEP;
        for (int t = 0; t < 88; ++t) {
            const int g = i * 88 + t;            // global step, [0,176)
            const int sA0 = q << 14;
            const int sB0 = w10(q + 1) << 14;
            const int sB1 = w10(q + 2) << 14;
            const int sA1 = w10(q + 3) << 14;
            const int stA1 = w10(q + 7) << 14;
            const int stA0 = w10(q + 8) << 14;
            const int stB0 = w10(q + 9) << 14;
            const int stB1 = sA0;                // turnaround

            {
                const int t1 = t + 1;
                if (i < 1 || t1 < 88)
                    stageA(128, (t1 >= 88 ? t1 - 88 : t1) * 64, stA1);
            }
            {
                const int t2 = t + 2;
                if (i < 1 || t2 < 88) {
                    stageA(0, (t2 >= 88 ? t2 - 88 : t2) * 64, stA0);
                    stageB((t2 >= 88 ? Bn : Bc), 0, (t2 >= 88 ? t2 - 88 : t2) * 64, stB0);
                }
            }

            short8 aF[4][4], bF[2][4];
#pragma unroll
            for (int ks = 0; ks < 4; ++ks) {
                aF[0][ks] = *(const short8*)(ldsc + sA0 + ibA[0][ks]);
                aF[1][ks] = *(const short8*)(ldsc + sA0 + ibA[1][ks]);
                aF[2][ks] = *(const short8*)(ldsc + sA1 + ibA[0][ks]);
                aF[3][ks] = *(const short8*)(ldsc + sA1 + ibA[1][ks]);
                bF[0][ks] = *(const short8*)(ldsc + sB0 + ibB[ks]);
                bF[1][ks] = *(const short8*)(ldsc + sB1 + ibB[ks]);
#pragma unroll
                for (int mt = 0; mt < 4; ++mt) {
                    acc[mt][0] = __builtin_amdgcn_mfma_f32_32x32x16_bf16(
                        aF[mt][ks], bF[0][ks], acc[mt][0], 0, 0, 0);
                    acc[mt][1] = __builtin_amdgcn_mfma_f32_32x32x16_bf16(
                        aF[mt][ks], bF[1][ks], acc[mt][1], 0, 0, 0);
                }
            }

            asm volatile("s_waitcnt lgkmcnt(0)" ::: "memory");
            __builtin_amdgcn_sched_barrier(0);
            asm volatile("s_barrier" ::: "memory");
            {
                const int t2 = t + 2;
                if (i < 1 || t2 < 88)
                    stageB((t2 >= 88 ? Bn : Bc), 128, (t2 >= 88 ? t2 - 88 : t2) * 64, stB1);
            }
            if (g < 174)       asm volatile("s_waitcnt vmcnt(6)" ::: "memory");
            else if (g == 174) asm volatile("s_waitcnt vmcnt(0)" ::: "memory");
            asm volatile("s_barrier" ::: "memory");
            q = w10(q + 4);
        }

        // Tile epilogue: fp32 store, then zero acc.
        const int n0i = (4 * i + nb) * 256;
        float* Ce = Cf + (size_t)e * TT * DIN;
#pragma unroll
        for (int mt = 0; mt < 4; ++mt) {
            const int row_b = m0 + (mt >> 1) * 128 + wr * 64 + (mt & 1) * 32 + 4 * lh;
#pragma unroll
            for (int nt = 0; nt < 2; ++nt) {
                const int col = n0i + nt * 128 + wc * 32 + l31;
#pragma unroll
                for (int j = 0; j < 16; ++j) {
                    const int row = row_b + (j & 3) + 8 * (j >> 2);
                    Ce[(size_t)row * DIN + col] = acc[mt][nt][j];
                }
            }
        }
#pragma unroll
        for (int mt = 0; mt < 4; ++mt)
#pragma unroll
            for (int nt = 0; nt < 2; ++nt)
#pragma unroll
                for (int j = 0; j < 16; ++j) acc[mt][nt][j] = 0.f;
        Bc = Bn;
    }
}

// out[z][C][opitch] (bf16) = convert(in[z][R][C] (f32)). 64x64 tiles.
__global__ __launch_bounds__(256) void transpose_f32_bf16(
    const float* __restrict__ in, unsigned short* __restrict__ out,
    int R, int C, int opitch, size_t ies, size_t oes)
{
    in  += (size_t)blockIdx.z * ies;
    out += (size_t)blockIdx.z * oes;
    __shared__ unsigned short t[64][65];
    const int tid = threadIdx.x;
    const int lr = tid >> 4, lc = (tid & 15) * 4;
    const int r0 = blockIdx.y * 64, c0 = blockIdx.x * 64;
#pragma unroll
    for (int i = 0; i < 4; ++i) {
        const int row = lr + i * 16;
        const float4 v = *(const float4*)(in + (size_t)(r0 + row) * C + c0 + lc);
        t[row][lc + 0] = f2bf(v.x); t[row][lc + 1] = f2bf(v.y);
        t[row][lc + 2] = f2bf(v.z); t[row][lc + 3] = f2bf(v.w);
    }
    __syncthreads();
#pragma unroll
    for (int i = 0; i < 4; ++i) {
        const int crow = lr + i * 16;
        ushort4 wv;
        wv.x = t[lc + 0][crow]; wv.y = t[lc + 1][crow];
        wv.z = t[lc + 2][crow]; wv.w = t[lc + 3][crow];
        *(ushort4*)(out + (size_t)(c0 + crow) * opitch + r0 + lc) = wv;
    }
}

// X [rows][2048] f32 -> [rows][KP] bf16 (row-padded).
__global__ __launch_bounds__(256) void conv_pad_f32_bf16(
    const float* __restrict__ in, unsigned short* __restrict__ out, int n8)
{
    int i = blockIdx.x * 256 + threadIdx.x;
    const int stride = gridDim.x * 256;
    for (; i < n8; i += stride) {
        const int row = i >> 8;                  // 256 chunks of 8 per row
        const int col = (i & 255) * 8;
        const float4 v0 = *(const float4*)(in + (size_t)row * DIN + col);
        const float4 v1 = *(const float4*)(in + (size_t)row * DIN + col + 4);
        ushort4 a, b;
        a.x = f2bf(v0.x); a.y = f2bf(v0.y); a.z = f2bf(v0.z); a.w = f2bf(v0.w);
        b.x = f2bf(v1.x); b.y = f2bf(v1.y); b.z = f2bf(v1.z); b.w = f2bf(v1.w);
        *(ushort4*)(out + (size_t)row * KP + col) = a;
        *(ushort4*)(out + (size_t)row * KP + col + 4) = b;
    }
}

extern "C" void kernel_launch(void* const* d_in, const int* in_sizes, int n_in,
                              void* d_out, int out_size, void* d_ws, size_t ws_size,
                              hipStream_t stream)
{
    const float* x  = (const float*)d_in[0];  // [E,T,DIN]
    const float* wg = (const float*)d_in[1];  // [E,DIN,DH]
    const float* wd = (const float*)d_in[2];  // [E,DIN,DH]
    const float* wu = (const float*)d_in[3];  // [E,DH,DIN]
    float* out = (float*)d_out;               // [E,T,DIN] fp32

    const size_t XSZ = (size_t)TT * KP;       // per-expert X elems (padded)
    const size_t WPSZ = (size_t)DH * KP;      // per-expert padded weight elems
    const size_t WSZ = (size_t)DIN * DH;      // per-expert WuT elems (unpadded)
    unsigned short* xb  = (unsigned short*)d_ws;      // [E] X bf16 padded  68 MB
    unsigned short* wgt = xb  + (size_t)NEXP * XSZ;   // [E] WgT / WuT     188 MB
    unsigned short* wdt = wgt + (size_t)NEXP * WPSZ;  // [E] WdT           188 MB
    unsigned short* hb  = wdt + (size_t)NEXP * WPSZ;  // [E] H             185 MB
    // total ws: ~628 MB

    // X -> bf16 padded rows
    conv_pad_f32_bf16<<<4096, 256, 0, stream>>>(x, xb, NEXP * TT * (DIN / 8));
    // WgT, WdT: [E][DH][KP] K-major padded
    transpose_f32_bf16<<<dim3(DH / 64, DIN / 64, NEXP), 256, 0, stream>>>(
        wg, wgt, DIN, DH, KP, WSZ, WPSZ);
    transpose_f32_bf16<<<dim3(DH / 64, DIN / 64, NEXP), 256, 0, stream>>>(
        wd, wdt, DIN, DH, KP, WSZ, WPSZ);
    // H = silu(X*Wg) * (X*Wd)   [E][T][DH]  — persistent fused dual-acc GEMM
    gemm_gu<<<256, 512, 0, stream>>>(xb, wgt, wdt, hb);
    // WuT: [E][DIN][DH] K-major, stride 5632 non-pow2 (reuse wgt region)
    transpose_f32_bf16<<<dim3(DIN / 64, DH / 64, NEXP), 256, 0, stream>>>(
        wu, wgt, DH, DIN, DH, WSZ, WSZ);
    // Out = H * Wu   [E][T][DIN] fp32  — persistent
    gemm_out<<<256, 512, 0, stream>>>(hb, wgt, out);
}